// Round 12
// baseline (464.499 us; speedup 1.0000x reference)
//
#include <hip/hip_runtime.h>
#include <hip/hip_bf16.h>

typedef unsigned short u16;
typedef __attribute__((ext_vector_type(8))) short short8;
typedef __attribute__((ext_vector_type(4))) float floatx4;

#define B_SZ 4
#define T_SZ 2048
#define C_SZ 1024
#define NH_SZ 16
#define HD_SZ 64
#define M_TOT 8192      // B*T
#define K_DIM 1024      // C

// fold softmax 1/sqrt(64) and log2(e) into Q's affine: scores land in log2 domain
#define QSCALE 0.1803368801111204f   // 0.125 * 1.4426950408889634

// workspace layout (u16 element offsets from ws base; all 16B-aligned)
#define OFF_XB   ((size_t)16)
#define OFF_WQT  (OFF_XB + 8388608)
#define OFF_WPT  (OFF_WQT + 3145728)
#define OFF_PB   (OFF_WPT + 1048576)
#define OFF_Q    (OFF_PB + 8192)
#define OFF_K    (OFF_Q + 8388608)
#define OFF_V    (OFF_K + 8388608)
#define OFF_Y    (OFF_V + 8388608)
// params sub-layout inside PB (contiguous: sources in order)
#define PB_BQKV  0
#define PB_BPROJ 3072
#define PB_QSC   4096
#define PB_QBI   5120
#define PB_KSC   6144
#define PB_KBI   7168

__device__ __forceinline__ float bf2f(u16 u) {
    return __uint_as_float(((unsigned)u) << 16);
}
__device__ __forceinline__ u16 f2bf(float f) {          // round-nearest-even
    unsigned x = __float_as_uint(f);
    unsigned r = (x + 0x7fffu + ((x >> 16) & 1u)) >> 16;
    return (u16)r;
}
__device__ __forceinline__ u16 f2bf_fast(float f) {     // round-half-up (cheap)
    return (u16)((__float_as_uint(f) + 0x8000u) >> 16);
}
// async global->LDS, 16B per lane; LDS dest = wave-uniform base + lane*16
__device__ __forceinline__ void gl_lds16(const u16* g, u16* l) {
    __builtin_amdgcn_global_load_lds(
        (const __attribute__((address_space(1))) void*)g,
        (__attribute__((address_space(3))) void*)l, 16, 0, 0);
}
// wave-uniform dtype detect from x[0:128] u16 (deterministic across blocks):
// fp32-reinterpreted-as-bf16 yields ~45 wild-exponent patterns; bf16 ~0.
__device__ __forceinline__ int detect_isf(const u16* xx, int lane) {
    float v0 = fabsf(bf2f(xx[lane * 2]));
    float v1 = fabsf(bf2f(xx[lane * 2 + 1]));
    int b0 = (v0 > 1024.0f) || (v0 != 0.0f && v0 < 9.5367431640625e-7f);
    int b1 = (v1 > 1024.0f) || (v1 != 0.0f && v1 < 9.5367431640625e-7f);
    unsigned long long ba = __ballot(b0), bb = __ballot(b1);
    return (__popcll(ba) + __popcll(bb)) > 8;
}

// ---- unified prep: x copy + params pack + both weight transposes ----------
// dtype flag computed wave-locally (no separate detect kernel); block 0
// thread 0 publishes it to ws for proj_gemm.
__global__ __launch_bounds__(256) void prep_k(
        const void* __restrict__ x,
        const void* __restrict__ Wqkv, const void* __restrict__ Wproj,
        const void* __restrict__ bqkv, const void* __restrict__ bproj,
        const void* __restrict__ qsc, const void* __restrict__ qbi,
        const void* __restrict__ ksc, const void* __restrict__ kbi,
        u16* __restrict__ xb, u16* __restrict__ Wt_qkv,
        u16* __restrict__ Wt_proj, u16* __restrict__ pb,
        int* __restrict__ flag) {
    __shared__ u16 t[32][33];
    const int blk = blockIdx.x;
    const int isf = detect_isf((const u16*)x, threadIdx.x & 63);
    if (blk == 0 && threadIdx.x == 0) flag[0] = isf;
    if (blk < 8192) {                       // x -> xb (4 elems/thread)
        const int i = blk * 256 + threadIdx.x;
        if (isf) {
            const float4 v = ((const float4*)x)[i];
            ushort4 o;
            o.x = f2bf(v.x); o.y = f2bf(v.y); o.z = f2bf(v.z); o.w = f2bf(v.w);
            ((ushort4*)xb)[i] = o;
        } else {
            ((ushort4*)xb)[i] = ((const ushort4*)x)[i];
        }
        return;
    }
    if (blk < 8200) {                       // small params -> pb
        const int i4 = (blk - 8192) * 256 + threadIdx.x;
        if (i4 >= 2048) return;
        const int e = i4 * 4;
        const void* src; int off;
        if (e < 3072)      { src = bqkv;  off = e; }
        else if (e < 4096) { src = bproj; off = e - 3072; }
        else if (e < 5120) { src = qsc;   off = e - 4096; }
        else if (e < 6144) { src = qbi;   off = e - 5120; }
        else if (e < 7168) { src = ksc;   off = e - 6144; }
        else               { src = kbi;   off = e - 7168; }
        ushort4 o;
        if (isf) {
            const float4 v = *(const float4*)((const float*)src + off);
            o.x = f2bf(v.x); o.y = f2bf(v.y); o.z = f2bf(v.z); o.w = f2bf(v.w);
        } else {
            o = *(const ushort4*)((const u16*)src + off);
        }
        *(ushort4*)&pb[e] = o;
        return;
    }
    const void* in; u16* out; int R, C, idx;
    if (blk < 11272) { idx = blk - 8200;  in = Wqkv;  out = Wt_qkv;  R = 1024; C = 3072; }
    else             { idx = blk - 11272; in = Wproj; out = Wt_proj; R = 1024; C = 1024; }
    const int nbx = C >> 5;
    const int c0 = (idx % nbx) * 32, r0 = (idx / nbx) * 32;
    const int tx = threadIdx.x & 31, ty = threadIdx.x >> 5;  // ty in 0..7
    for (int i = 0; i < 4; i++) {
        int r = ty + i * 8;
        size_t gi = (size_t)(r0 + r) * C + c0 + tx;
        t[r][tx] = isf ? f2bf(((const float*)in)[gi]) : ((const u16*)in)[gi];
    }
    __syncthreads();
    for (int i = 0; i < 4; i++) {
        int cr = ty + i * 8;
        out[(size_t)(c0 + cr) * R + r0 + tx] = t[tx][cr];
    }
}

// ---------------- QKV GEMM (R8 structure): BK=64, gl_lds, XOR swizzle ------
__global__ __launch_bounds__(256) void qkv_gemm(
        const u16* __restrict__ X, const u16* __restrict__ Wt,
        const u16* __restrict__ pb,
        u16* __restrict__ Qb, u16* __restrict__ Kb, u16* __restrict__ Vb) {
    __shared__ __align__(16) u16 As[128 * 64];
    __shared__ __align__(16) u16 Bs[128 * 64];
    const int bm = blockIdx.y * 128, bn = blockIdx.x * 128;
    const int tid = threadIdx.x;
    const int lane = tid & 63, wave = tid >> 6;
    const int quad = lane >> 4, l16 = lane & 15;
    const int wm = (wave & 1) * 64, wn = (wave >> 1) * 64;
    const int lrow = lane >> 3;                       // 8 rows per inst
    const int lcol = ((lane & 7) ^ lrow) * 8;         // swizzled source chunk

    floatx4 acc[4][4];
    for (int mi = 0; mi < 4; mi++)
        for (int ni = 0; ni < 4; ni++) acc[mi][ni] = 0.f;

    for (int k0 = 0; k0 < K_DIM; k0 += 64) {
        __syncthreads();
        for (int j = 0; j < 4; j++) {
            const int rb = wave * 32 + j * 8;
            gl_lds16(&X[(size_t)(bm + rb + lrow) * K_DIM + k0 + lcol], &As[rb * 64]);
            gl_lds16(&Wt[(size_t)(bn + rb + lrow) * K_DIM + k0 + lcol], &Bs[rb * 64]);
        }
        __syncthreads();
        for (int kk = 0; kk < 64; kk += 32) {
            const int cb = kk >> 3;                   // 0 or 4
            const int slot = ((cb + quad) ^ (l16 & 7)) * 8;
            short8 a[4], b[4];
            for (int mi = 0; mi < 4; mi++)
                a[mi] = *(const short8*)&As[(wm + mi * 16 + l16) * 64 + slot];
            for (int ni = 0; ni < 4; ni++)
                b[ni] = *(const short8*)&Bs[(wn + ni * 16 + l16) * 64 + slot];
            for (int mi = 0; mi < 4; mi++)
                for (int ni = 0; ni < 4; ni++)
                    acc[mi][ni] = __builtin_amdgcn_mfma_f32_16x16x32_bf16(
                        a[mi], b[ni], acc[mi][ni], 0, 0, 0);
        }
    }

    const int sec = bn >> 10;  // 0=q 1=k 2=v (128-tile never crosses 1024)
    const int bb = bm >> 11;   // batch index (constant per block)
    const int tbase = bm & 2047;
    for (int mi = 0; mi < 4; mi++) {
        for (int ni = 0; ni < 4; ni++) {
            const int col = bn + wn + ni * 16 + l16;
            const int cmod = col & 1023;
            const int h = cmod >> 6, d = cmod & 63;
            const float bv = bf2f(pb[PB_BQKV + col]);
            if (sec == 2) {
                const int t0 = tbase + wm + mi * 16 + quad * 4;
                ushort4 pk;
                pk.x = f2bf(acc[mi][ni][0] + bv);
                pk.y = f2bf(acc[mi][ni][1] + bv);
                pk.z = f2bf(acc[mi][ni][2] + bv);
                pk.w = f2bf(acc[mi][ni][3] + bv);
                *(ushort4*)&Vb[(((size_t)(bb * NH_SZ + h)) * HD_SZ + d) * T_SZ + t0] = pk;
            } else {
                float sA, sB;
                if (sec == 0) {
                    sA = bf2f(pb[PB_QSC + h * 64 + d]) * QSCALE;
                    sB = bf2f(pb[PB_QBI + h * 64 + d]) * QSCALE;
                } else {
                    sA = bf2f(pb[PB_KSC + h * 64 + d]);
                    sB = bf2f(pb[PB_KBI + h * 64 + d]);
                }
                u16* dstbuf = (sec == 0) ? Qb : Kb;
                for (int r = 0; r < 4; r++) {
                    const int t = tbase + wm + mi * 16 + quad * 4 + r;
                    float v = (acc[mi][ni][r] + bv) * sA + sB;
                    dstbuf[(((size_t)(bb * NH_SZ + h)) * T_SZ + t) * HD_SZ + d] = f2bf(v);
                }
            }
        }
    }
}

// -------- Flash attention: 128-key stages (halved barrier count) -----------
// Uniform makespan pairing (17 staging iters/block). S^T formulation (lane
// owns one q-row). K/V staged via global_load_lds + XOR chunk swizzle
// (K: 8-chunk rows; V: 16-chunk rows). Per-ni-group skipping on the diagonal
// stage. Row-sum via ones-MFMA. Ps stride 136 u16 (odd dword multiplier ->
// conflict-free b128 reads). No min-waves launch bound (R10 spill lesson).
__global__ __launch_bounds__(512) void attn_k(const u16* __restrict__ Qb,
                                              const u16* __restrict__ Kb,
                                              const u16* __restrict__ Vtg,
                                              u16* __restrict__ Y) {
    __shared__ __align__(16) u16 Ks[128 * 64];      // [key][d]
    __shared__ __align__(16) u16 Vs[64 * 128];      // [d][key]
    __shared__ __align__(16) u16 Ps[8 * 16 * 136];  // per-wave P^T [q][key]
    const int blk = blockIdx.x;
    const int head = blk & 63;          // b*NH + h
    const int p = blk >> 6;             // pair index 0..7
    const int b = head >> 4, h = head & 15;
    const int tid = threadIdx.x, lane = tid & 63, w = tid >> 6;
    const int quad = lane >> 4, l16 = lane & 15;
    const size_t qk_off = (size_t)head * (T_SZ * HD_SZ);
    const size_t v_off = (size_t)head * (HD_SZ * T_SZ);
    u16* psw = &Ps[w * 2176];           // wave-private P^T region
    const int lr = lane >> 3;                         // K staging row-in-group
    const int lck = ((lane & 7) ^ lr) * 8;            // K swizzled source chunk
    const int vrow_in = lane >> 4;                    // V staging row-in-group
    const int vch = lane & 15;                        // V dest chunk (hw-fixed)
    const int e3 = l16 & 7;
    const int sl0 = ((0 + quad) ^ e3) * 8;            // K d-chunk read slots
    const int sl1 = ((4 + quad) ^ e3) * 8;

    short8 ones;
    for (int j = 0; j < 8; j++) ones[j] = (short)0x3F80;  // bf16 1.0

    for (int tile = 0; tile < 2; tile++) {
        const int qt = tile ? p : (15 - p);
        const int q0 = qt * 128;
        const int rbase = q0 + w * 16;  // wave's first q row
        const int q = rbase + l16;      // this lane's q row

        const short8 aq0 = *(const short8*)&Qb[qk_off + (size_t)q * HD_SZ + quad * 8];
        const short8 aq1 = *(const short8*)&Qb[qk_off + (size_t)q * HD_SZ + 32 + quad * 8];

        floatx4 o[4];                   // o^T: col=q(lane), rows=d-group mi
        for (int mi = 0; mi < 4; mi++) o[mi] = 0.f;
        float m_run = -1e30f, l_run = 0.f;

        for (int k0 = 0; k0 < q0 + 128; k0 += 128) {
            __syncthreads();
            for (int j = 0; j < 2; j++) {
                gl_lds16(&Kb[qk_off + (size_t)(k0 + w * 16 + j * 8 + lr) * HD_SZ + lck],
                         &Ks[(w * 16 + j * 8) * 64]);
                const int dr = w * 8 + j * 4 + vrow_in;
                gl_lds16(&Vtg[v_off + (size_t)dr * T_SZ + k0 + ((vch ^ (dr & 7)) * 8)],
                         &Vs[(w * 8 + j * 4) * 128]);
            }
            __syncthreads();
            const int ak_raw = rbase + 16 - k0;
            if (ak_raw <= 0) continue;  // fully masked for this wave
            const int akeys = (ak_raw < 128) ? ak_raw : 128;
            const int nact = akeys >> 4;            // active 16-key groups
            const bool diag = (ak_raw <= 128);      // stage contains diagonal

            // S^T[key][q]: A = K fragments, B = Q fragment (active groups only)
            floatx4 s[8];
            for (int ni = 0; ni < nact; ni++) s[ni] = 0.f;
            for (int ni = 0; ni < nact; ni++)
                s[ni] = __builtin_amdgcn_mfma_f32_16x16x32_bf16(
                    *(const short8*)&Ks[(ni * 16 + l16) * 64 + sl0], aq0, s[ni], 0, 0, 0);
            for (int ni = 0; ni < nact; ni++)
                s[ni] = __builtin_amdgcn_mfma_f32_16x16x32_bf16(
                    *(const short8*)&Ks[(ni * 16 + l16) * 64 + sl1], aq1, s[ni], 0, 0, 0);

            if (diag) {
                // last active group holds keys rbase..rbase+15: mask is
                // lane-local: key_local = quad*4+r vs l16
                const int nd = nact - 1;
                for (int r = 0; r < 4; r++)
                    if (quad * 4 + r > l16) s[nd][r] = -1e30f;
            }

            float mx = -1e30f;
            for (int ni = 0; ni < nact; ni++)
                mx = fmaxf(mx, fmaxf(fmaxf(s[ni][0], s[ni][1]),
                                     fmaxf(s[ni][2], s[ni][3])));
            mx = fmaxf(mx, __shfl_xor(mx, 16, 64));
            mx = fmaxf(mx, __shfl_xor(mx, 32, 64));
            const float mnew = fmaxf(m_run, mx);
            const float alpha = exp2f(m_run - mnew);
            for (int ni = 0; ni < nact; ni++)
                for (int r = 0; r < 4; r++)
                    s[ni][r] = exp2f(s[ni][r] - mnew);
            m_run = mnew;
            for (int mi = 0; mi < 4; mi++) o[mi] *= alpha;

            // P^T store (zero inactive groups up to the 32-key PV granule)
            for (int ni = 0; ni < 8; ni++) {
                ushort4 pk;
                if (ni < nact) {
                    pk.x = f2bf_fast(s[ni][0]); pk.y = f2bf_fast(s[ni][1]);
                    pk.z = f2bf_fast(s[ni][2]); pk.w = f2bf_fast(s[ni][3]);
                } else {
                    pk.x = 0; pk.y = 0; pk.z = 0; pk.w = 0;
                }
                *(ushort4*)&psw[l16 * 136 + ni * 16 + quad * 4] = pk;
            }

            // o^T[d][q] += V^T * P^T over active 32-key granules
            floatx4 s4 = 0.f;
            for (int kk = 0; kk < akeys; kk += 32) {
                short8 pfr = *(const short8*)&psw[l16 * 136 + kk + quad * 8];
                s4 = __builtin_amdgcn_mfma_f32_16x16x32_bf16(ones, pfr, s4, 0, 0, 0);
                const int vsl = (((kk >> 3) + quad) ^ e3) * 8;
                for (int mi = 0; mi < 4; mi++) {
                    short8 vfr = *(const short8*)&Vs[(mi * 16 + l16) * 128 + vsl];
                    o[mi] = __builtin_amdgcn_mfma_f32_16x16x32_bf16(vfr, pfr, o[mi], 0, 0, 0);
                }
            }
            l_run = l_run * alpha + s4[0];
        }

        const float inv = 1.0f / l_run;
        u16* yrow = &Y[(((size_t)b * T_SZ + q) * NH_SZ + h) * HD_SZ];
        for (int mi = 0; mi < 4; mi++) {
            ushort4 pk;
            pk.x = f2bf_fast(o[mi][0] * inv); pk.y = f2bf_fast(o[mi][1] * inv);
            pk.z = f2bf_fast(o[mi][2] * inv); pk.w = f2bf_fast(o[mi][3] * inv);
            *(ushort4*)&yrow[mi * 16 + quad * 4] = pk;
        }
    }
}

// ---------------- Proj GEMM (R8 structure) ---------------------------------
__global__ __launch_bounds__(256) void proj_gemm(const u16* __restrict__ Yin,
                                                 const u16* __restrict__ Wt,
                                                 const u16* __restrict__ pb,
                                                 void* __restrict__ out,
                                                 const int* __restrict__ flag) {
    __shared__ __align__(16) u16 As[128 * 64];
    __shared__ __align__(16) u16 Bs[128 * 64];
    const int isf = flag[0];
    const int bm = blockIdx.y * 128, bn = blockIdx.x * 128;
    const int tid = threadIdx.x;
    const int lane = tid & 63, wave = tid >> 6;
    const int quad = lane >> 4, l16 = lane & 15;
    const int wm = (wave & 1) * 64, wn = (wave >> 1) * 64;
    const int lrow = lane >> 3;
    const int lcol = ((lane & 7) ^ lrow) * 8;         // swizzled source chunk

    floatx4 acc[4][4];
    for (int mi = 0; mi < 4; mi++)
        for (int ni = 0; ni < 4; ni++) acc[mi][ni] = 0.f;

    for (int k0 = 0; k0 < K_DIM; k0 += 64) {
        __syncthreads();
        for (int j = 0; j < 4; j++) {
            const int rb = wave * 32 + j * 8;
            gl_lds16(&Yin[(size_t)(bm + rb + lrow) * K_DIM + k0 + lcol], &As[rb * 64]);
            gl_lds16(&Wt[(size_t)(bn + rb + lrow) * K_DIM + k0 + lcol], &Bs[rb * 64]);
        }
        __syncthreads();
        for (int kk = 0; kk < 64; kk += 32) {
            const int cb = kk >> 3;
            const int slot = ((cb + quad) ^ (l16 & 7)) * 8;
            short8 a[4], b[4];
            for (int mi = 0; mi < 4; mi++)
                a[mi] = *(const short8*)&As[(wm + mi * 16 + l16) * 64 + slot];
            for (int ni = 0; ni < 4; ni++)
                b[ni] = *(const short8*)&Bs[(wn + ni * 16 + l16) * 64 + slot];
            for (int mi = 0; mi < 4; mi++)
                for (int ni = 0; ni < 4; ni++)
                    acc[mi][ni] = __builtin_amdgcn_mfma_f32_16x16x32_bf16(
                        a[mi], b[ni], acc[mi][ni], 0, 0, 0);
        }
    }

    for (int mi = 0; mi < 4; mi++) {
        for (int ni = 0; ni < 4; ni++) {
            const int col = bn + wn + ni * 16 + l16;
            const float bv = bf2f(pb[PB_BPROJ + col]);
            for (int r = 0; r < 4; r++) {
                const int row = bm + wm + mi * 16 + quad * 4 + r;
                const float v = acc[mi][ni][r] + bv;
                if (isf) ((float*)out)[(size_t)row * C_SZ + col] = v;
                else     ((u16*)out)[(size_t)row * C_SZ + col] = f2bf(v);
            }
        }
    }
}

extern "C" void kernel_launch(void* const* d_in, const int* in_sizes, int n_in,
                              void* d_out, int out_size, void* d_ws, size_t ws_size,
                              hipStream_t stream) {
    const void* x     = d_in[0];
    const void* Wqkv  = d_in[1];
    const void* bqkv  = d_in[2];
    const void* Wproj = d_in[3];
    const void* bproj = d_in[4];
    const void* qsc   = d_in[5];
    const void* qbi   = d_in[6];
    const void* ksc   = d_in[7];
    const void* kbi   = d_in[8];

    u16* ws = (u16*)d_ws;
    int* flag    = (int*)d_ws;
    u16* xb      = ws + OFF_XB;
    u16* Wt_qkv  = ws + OFF_WQT;
    u16* Wt_proj = ws + OFF_WPT;
    u16* pb      = ws + OFF_PB;
    u16* Qb      = ws + OFF_Q;
    u16* Kb      = ws + OFF_K;
    u16* Vb      = ws + OFF_V;     // [B,NH,HD,T]
    u16* Yb      = ws + OFF_Y;

    prep_k<<<12296, 256, 0, stream>>>(x, Wqkv, Wproj, bqkv, bproj,
                                      qsc, qbi, ksc, kbi,
                                      xb, Wt_qkv, Wt_proj, pb, flag);
    qkv_gemm<<<dim3(24, 64), 256, 0, stream>>>(xb, Wt_qkv, pb, Qb, Kb, Vb);
    attn_k<<<dim3(512), 512, 0, stream>>>(Qb, Kb, Vb, Yb);
    proj_gemm<<<dim3(8, 64), 256, 0, stream>>>(Yb, Wt_proj, pb, d_out, flag);
}

// Round 13
// 305.502 us; speedup vs baseline: 1.5204x; 1.5204x over previous
//
#include <hip/hip_runtime.h>
#include <hip/hip_bf16.h>

typedef unsigned short u16;
typedef __attribute__((ext_vector_type(8))) short short8;
typedef __attribute__((ext_vector_type(4))) float floatx4;

#define B_SZ 4
#define T_SZ 2048
#define C_SZ 1024
#define NH_SZ 16
#define HD_SZ 64
#define M_TOT 8192      // B*T
#define K_DIM 1024      // C

// fold softmax 1/sqrt(64) and log2(e) into Q's affine: scores land in log2 domain
#define QSCALE 0.1803368801111204f   // 0.125 * 1.4426950408889634

// workspace layout (u16 element offsets from ws base; all 16B-aligned)
#define OFF_XB   ((size_t)16)
#define OFF_WQT  (OFF_XB + 8388608)
#define OFF_WPT  (OFF_WQT + 3145728)
#define OFF_PB   (OFF_WPT + 1048576)
#define OFF_Q    (OFF_PB + 8192)
#define OFF_K    (OFF_Q + 8388608)
#define OFF_V    (OFF_K + 8388608)
#define OFF_Y    (OFF_V + 8388608)
// params sub-layout inside PB (contiguous: sources in order)
#define PB_BQKV  0
#define PB_BPROJ 3072
#define PB_QSC   4096
#define PB_QBI   5120
#define PB_KSC   6144
#define PB_KBI   7168

__device__ __forceinline__ float bf2f(u16 u) {
    return __uint_as_float(((unsigned)u) << 16);
}
__device__ __forceinline__ u16 f2bf(float f) {          // round-nearest-even
    unsigned x = __float_as_uint(f);
    unsigned r = (x + 0x7fffu + ((x >> 16) & 1u)) >> 16;
    return (u16)r;
}
__device__ __forceinline__ u16 f2bf_fast(float f) {     // round-half-up (cheap)
    return (u16)((__float_as_uint(f) + 0x8000u) >> 16);
}
// async global->LDS, 16B per lane; LDS dest = wave-uniform base + lane*16
__device__ __forceinline__ void gl_lds16(const u16* g, u16* l) {
    __builtin_amdgcn_global_load_lds(
        (const __attribute__((address_space(1))) void*)g,
        (__attribute__((address_space(3))) void*)l, 16, 0, 0);
}
// wave-uniform dtype detect from x[0:128] u16 (deterministic across blocks):
// fp32-reinterpreted-as-bf16 yields ~45 wild-exponent patterns; bf16 ~0.
// Validated in R12 (passed with fp32 inputs).
__device__ __forceinline__ int detect_isf(const u16* xx, int lane) {
    float v0 = fabsf(bf2f(xx[lane * 2]));
    float v1 = fabsf(bf2f(xx[lane * 2 + 1]));
    int b0 = (v0 > 1024.0f) || (v0 != 0.0f && v0 < 9.5367431640625e-7f);
    int b1 = (v1 > 1024.0f) || (v1 != 0.0f && v1 < 9.5367431640625e-7f);
    unsigned long long ba = __ballot(b0), bb = __ballot(b1);
    return (__popcll(ba) + __popcll(bb)) > 8;
}

// ---- unified prep: x copy + params pack + both weight transposes ----------
// dtype flag computed wave-locally; block 0 publishes it for proj_gemm.
__global__ __launch_bounds__(256) void prep_k(
        const void* __restrict__ x,
        const void* __restrict__ Wqkv, const void* __restrict__ Wproj,
        const void* __restrict__ bqkv, const void* __restrict__ bproj,
        const void* __restrict__ qsc, const void* __restrict__ qbi,
        const void* __restrict__ ksc, const void* __restrict__ kbi,
        u16* __restrict__ xb, u16* __restrict__ Wt_qkv,
        u16* __restrict__ Wt_proj, u16* __restrict__ pb,
        int* __restrict__ flag) {
    __shared__ u16 t[32][33];
    const int blk = blockIdx.x;
    const int isf = detect_isf((const u16*)x, threadIdx.x & 63);
    if (blk == 0 && threadIdx.x == 0) flag[0] = isf;
    if (blk < 8192) {                       // x -> xb (4 elems/thread)
        const int i = blk * 256 + threadIdx.x;
        if (isf) {
            const float4 v = ((const float4*)x)[i];
            ushort4 o;
            o.x = f2bf(v.x); o.y = f2bf(v.y); o.z = f2bf(v.z); o.w = f2bf(v.w);
            ((ushort4*)xb)[i] = o;
        } else {
            ((ushort4*)xb)[i] = ((const ushort4*)x)[i];
        }
        return;
    }
    if (blk < 8200) {                       // small params -> pb
        const int i4 = (blk - 8192) * 256 + threadIdx.x;
        if (i4 >= 2048) return;
        const int e = i4 * 4;
        const void* src; int off;
        if (e < 3072)      { src = bqkv;  off = e; }
        else if (e < 4096) { src = bproj; off = e - 3072; }
        else if (e < 5120) { src = qsc;   off = e - 4096; }
        else if (e < 6144) { src = qbi;   off = e - 5120; }
        else if (e < 7168) { src = ksc;   off = e - 6144; }
        else               { src = kbi;   off = e - 7168; }
        ushort4 o;
        if (isf) {
            const float4 v = *(const float4*)((const float*)src + off);
            o.x = f2bf(v.x); o.y = f2bf(v.y); o.z = f2bf(v.z); o.w = f2bf(v.w);
        } else {
            o = *(const ushort4*)((const u16*)src + off);
        }
        *(ushort4*)&pb[e] = o;
        return;
    }
    const void* in; u16* out; int R, C, idx;
    if (blk < 11272) { idx = blk - 8200;  in = Wqkv;  out = Wt_qkv;  R = 1024; C = 3072; }
    else             { idx = blk - 11272; in = Wproj; out = Wt_proj; R = 1024; C = 1024; }
    const int nbx = C >> 5;
    const int c0 = (idx % nbx) * 32, r0 = (idx / nbx) * 32;
    const int tx = threadIdx.x & 31, ty = threadIdx.x >> 5;  // ty in 0..7
    for (int i = 0; i < 4; i++) {
        int r = ty + i * 8;
        size_t gi = (size_t)(r0 + r) * C + c0 + tx;
        t[r][tx] = isf ? f2bf(((const float*)in)[gi]) : ((const u16*)in)[gi];
    }
    __syncthreads();
    for (int i = 0; i < 4; i++) {
        int cr = ty + i * 8;
        out[(size_t)(c0 + cr) * R + r0 + tx] = t[tx][cr];
    }
}

// ---------------- QKV GEMM (R8 structure): BK=64, gl_lds, XOR swizzle ------
__global__ __launch_bounds__(256) void qkv_gemm(
        const u16* __restrict__ X, const u16* __restrict__ Wt,
        const u16* __restrict__ pb,
        u16* __restrict__ Qb, u16* __restrict__ Kb, u16* __restrict__ Vb) {
    __shared__ __align__(16) u16 As[128 * 64];
    __shared__ __align__(16) u16 Bs[128 * 64];
    const int bm = blockIdx.y * 128, bn = blockIdx.x * 128;
    const int tid = threadIdx.x;
    const int lane = tid & 63, wave = tid >> 6;
    const int quad = lane >> 4, l16 = lane & 15;
    const int wm = (wave & 1) * 64, wn = (wave >> 1) * 64;
    const int lrow = lane >> 3;                       // 8 rows per inst
    const int lcol = ((lane & 7) ^ lrow) * 8;         // swizzled source chunk

    floatx4 acc[4][4];
    for (int mi = 0; mi < 4; mi++)
        for (int ni = 0; ni < 4; ni++) acc[mi][ni] = 0.f;

    for (int k0 = 0; k0 < K_DIM; k0 += 64) {
        __syncthreads();
        for (int j = 0; j < 4; j++) {
            const int rb = wave * 32 + j * 8;
            gl_lds16(&X[(size_t)(bm + rb + lrow) * K_DIM + k0 + lcol], &As[rb * 64]);
            gl_lds16(&Wt[(size_t)(bn + rb + lrow) * K_DIM + k0 + lcol], &Bs[rb * 64]);
        }
        __syncthreads();
        for (int kk = 0; kk < 64; kk += 32) {
            const int cb = kk >> 3;                   // 0 or 4
            const int slot = ((cb + quad) ^ (l16 & 7)) * 8;
            short8 a[4], b[4];
            for (int mi = 0; mi < 4; mi++)
                a[mi] = *(const short8*)&As[(wm + mi * 16 + l16) * 64 + slot];
            for (int ni = 0; ni < 4; ni++)
                b[ni] = *(const short8*)&Bs[(wn + ni * 16 + l16) * 64 + slot];
            for (int mi = 0; mi < 4; mi++)
                for (int ni = 0; ni < 4; ni++)
                    acc[mi][ni] = __builtin_amdgcn_mfma_f32_16x16x32_bf16(
                        a[mi], b[ni], acc[mi][ni], 0, 0, 0);
        }
    }

    const int sec = bn >> 10;  // 0=q 1=k 2=v (128-tile never crosses 1024)
    const int bb = bm >> 11;   // batch index (constant per block)
    const int tbase = bm & 2047;
    for (int mi = 0; mi < 4; mi++) {
        for (int ni = 0; ni < 4; ni++) {
            const int col = bn + wn + ni * 16 + l16;
            const int cmod = col & 1023;
            const int h = cmod >> 6, d = cmod & 63;
            const float bv = bf2f(pb[PB_BQKV + col]);
            if (sec == 2) {
                const int t0 = tbase + wm + mi * 16 + quad * 4;
                ushort4 pk;
                pk.x = f2bf(acc[mi][ni][0] + bv);
                pk.y = f2bf(acc[mi][ni][1] + bv);
                pk.z = f2bf(acc[mi][ni][2] + bv);
                pk.w = f2bf(acc[mi][ni][3] + bv);
                *(ushort4*)&Vb[(((size_t)(bb * NH_SZ + h)) * HD_SZ + d) * T_SZ + t0] = pk;
            } else {
                float sA, sB;
                if (sec == 0) {
                    sA = bf2f(pb[PB_QSC + h * 64 + d]) * QSCALE;
                    sB = bf2f(pb[PB_QBI + h * 64 + d]) * QSCALE;
                } else {
                    sA = bf2f(pb[PB_KSC + h * 64 + d]);
                    sB = bf2f(pb[PB_KBI + h * 64 + d]);
                }
                u16* dstbuf = (sec == 0) ? Qb : Kb;
                for (int r = 0; r < 4; r++) {
                    const int t = tbase + wm + mi * 16 + quad * 4 + r;
                    float v = (acc[mi][ni][r] + bv) * sA + sB;
                    dstbuf[(((size_t)(bb * NH_SZ + h)) * T_SZ + t) * HD_SZ + d] = f2bf(v);
                }
            }
        }
    }
}

// -------- Flash attention (R8/R11 structure, proven best) ------------------
// Uniform makespan pairing (34 k-iters/block, 64-key stages, fixed unrolls).
// S^T formulation (lane owns one q-row). K/V staged via global_load_lds +
// XOR chunk swizzle. Row-sum via ones-MFMA. Cheap bf16 converts in hot loop.
__global__ __launch_bounds__(512) void attn_k(const u16* __restrict__ Qb,
                                              const u16* __restrict__ Kb,
                                              const u16* __restrict__ Vtg,
                                              u16* __restrict__ Y) {
    __shared__ __align__(16) u16 Ks[64 * 64];       // [key][d], swizzled chunks
    __shared__ __align__(16) u16 Vs[64 * 64];       // [d][key], swizzled chunks
    __shared__ __align__(16) u16 Ps[8 * 16 * 88];   // per-wave P^T [q][key], stride 88
    const int blk = blockIdx.x;
    const int head = blk & 63;          // b*NH + h
    const int p = blk >> 6;             // pair index 0..7
    const int b = head >> 4, h = head & 15;
    const int tid = threadIdx.x, lane = tid & 63, w = tid >> 6;
    const int quad = lane >> 4, l16 = lane & 15;
    const size_t qk_off = (size_t)head * (T_SZ * HD_SZ);
    const size_t v_off = (size_t)head * (HD_SZ * T_SZ);
    u16* psw = &Ps[w * 1408];           // wave-private P^T region
    const int lr = lane >> 3;                     // staging row within wave group
    const int lc = ((lane & 7) ^ lr) * 8;         // swizzled source chunk
    const int sl0 = ((quad) ^ (l16 & 7)) * 8;         // kk = 0
    const int sl1 = ((4 + quad) ^ (l16 & 7)) * 8;     // kk = 32

    short8 ones;
    for (int j = 0; j < 8; j++) ones[j] = (short)0x3F80;  // bf16 1.0

    for (int tile = 0; tile < 2; tile++) {
        const int qt = tile ? p : (15 - p);
        const int q0 = qt * 128;
        const int rbase = q0 + w * 16;  // wave's first q row
        const int q = rbase + l16;      // this lane's q row

        const short8 aq0 = *(const short8*)&Qb[qk_off + (size_t)q * HD_SZ + quad * 8];
        const short8 aq1 = *(const short8*)&Qb[qk_off + (size_t)q * HD_SZ + 32 + quad * 8];

        floatx4 o[4];                   // o^T: col=q(lane), rows=d-group mi
        for (int mi = 0; mi < 4; mi++) o[mi] = 0.f;
        float m_run = -1e30f, l_run = 0.f;

        for (int k0 = 0; k0 < q0 + 128; k0 += 64) {
            __syncthreads();
            gl_lds16(&Kb[qk_off + (size_t)(k0 + w * 8 + lr) * HD_SZ + lc], &Ks[w * 512]);
            gl_lds16(&Vtg[v_off + (size_t)(w * 8 + lr) * T_SZ + k0 + lc], &Vs[w * 512]);
            __syncthreads();
            if (k0 > rbase + 15) continue;  // fully masked for this wave

            floatx4 s[4];
            for (int ni = 0; ni < 4; ni++) s[ni] = 0.f;
            for (int ni = 0; ni < 4; ni++)
                s[ni] = __builtin_amdgcn_mfma_f32_16x16x32_bf16(
                    *(const short8*)&Ks[(ni * 16 + l16) * 64 + sl0], aq0, s[ni], 0, 0, 0);
            for (int ni = 0; ni < 4; ni++)
                s[ni] = __builtin_amdgcn_mfma_f32_16x16x32_bf16(
                    *(const short8*)&Ks[(ni * 16 + l16) * 64 + sl1], aq1, s[ni], 0, 0, 0);

            if (k0 + 63 > rbase) {          // tile touches the diagonal
                for (int ni = 0; ni < 4; ni++)
                    for (int r = 0; r < 4; r++) {
                        int key = k0 + ni * 16 + quad * 4 + r;
                        if (key > q) s[ni][r] = -1e30f;
                    }
            }

            float mx = fmaxf(fmaxf(s[0][0], s[0][1]), fmaxf(s[0][2], s[0][3]));
            for (int ni = 1; ni < 4; ni++)
                mx = fmaxf(mx, fmaxf(fmaxf(s[ni][0], s[ni][1]),
                                     fmaxf(s[ni][2], s[ni][3])));
            mx = fmaxf(mx, __shfl_xor(mx, 16, 64));
            mx = fmaxf(mx, __shfl_xor(mx, 32, 64));
            const float mnew = fmaxf(m_run, mx);
            const float alpha = exp2f(m_run - mnew);
            for (int ni = 0; ni < 4; ni++)
                for (int r = 0; r < 4; r++)
                    s[ni][r] = exp2f(s[ni][r] - mnew);
            m_run = mnew;
            for (int mi = 0; mi < 4; mi++) o[mi] *= alpha;

            for (int ni = 0; ni < 4; ni++) {
                ushort4 pk;
                pk.x = f2bf_fast(s[ni][0]); pk.y = f2bf_fast(s[ni][1]);
                pk.z = f2bf_fast(s[ni][2]); pk.w = f2bf_fast(s[ni][3]);
                *(ushort4*)&psw[l16 * 88 + ni * 16 + quad * 4] = pk;
            }

            floatx4 s4 = 0.f;
            for (int kk = 0; kk < 64; kk += 32) {
                short8 pfr = *(const short8*)&psw[l16 * 88 + kk + quad * 8];
                const int vsl = (kk == 0) ? sl0 : sl1;
                s4 = __builtin_amdgcn_mfma_f32_16x16x32_bf16(ones, pfr, s4, 0, 0, 0);
                for (int mi = 0; mi < 4; mi++) {
                    short8 vfr = *(const short8*)&Vs[(mi * 16 + l16) * 64 + vsl];
                    o[mi] = __builtin_amdgcn_mfma_f32_16x16x32_bf16(vfr, pfr, o[mi], 0, 0, 0);
                }
            }
            l_run = l_run * alpha + s4[0];
        }

        const float inv = 1.0f / l_run;
        u16* yrow = &Y[(((size_t)b * T_SZ + q) * NH_SZ + h) * HD_SZ];
        for (int mi = 0; mi < 4; mi++) {
            ushort4 pk;
            pk.x = f2bf_fast(o[mi][0] * inv); pk.y = f2bf_fast(o[mi][1] * inv);
            pk.z = f2bf_fast(o[mi][2] * inv); pk.w = f2bf_fast(o[mi][3] * inv);
            *(ushort4*)&yrow[mi * 16 + quad * 4] = pk;
        }
    }
}

// ---------------- Proj GEMM (R8 structure) ---------------------------------
__global__ __launch_bounds__(256) void proj_gemm(const u16* __restrict__ Yin,
                                                 const u16* __restrict__ Wt,
                                                 const u16* __restrict__ pb,
                                                 void* __restrict__ out,
                                                 const int* __restrict__ flag) {
    __shared__ __align__(16) u16 As[128 * 64];
    __shared__ __align__(16) u16 Bs[128 * 64];
    const int isf = flag[0];
    const int bm = blockIdx.y * 128, bn = blockIdx.x * 128;
    const int tid = threadIdx.x;
    const int lane = tid & 63, wave = tid >> 6;
    const int quad = lane >> 4, l16 = lane & 15;
    const int wm = (wave & 1) * 64, wn = (wave >> 1) * 64;
    const int lrow = lane >> 3;
    const int lcol = ((lane & 7) ^ lrow) * 8;         // swizzled source chunk

    floatx4 acc[4][4];
    for (int mi = 0; mi < 4; mi++)
        for (int ni = 0; ni < 4; ni++) acc[mi][ni] = 0.f;

    for (int k0 = 0; k0 < K_DIM; k0 += 64) {
        __syncthreads();
        for (int j = 0; j < 4; j++) {
            const int rb = wave * 32 + j * 8;
            gl_lds16(&Yin[(size_t)(bm + rb + lrow) * K_DIM + k0 + lcol], &As[rb * 64]);
            gl_lds16(&Wt[(size_t)(bn + rb + lrow) * K_DIM + k0 + lcol], &Bs[rb * 64]);
        }
        __syncthreads();
        for (int kk = 0; kk < 64; kk += 32) {
            const int cb = kk >> 3;
            const int slot = ((cb + quad) ^ (l16 & 7)) * 8;
            short8 a[4], b[4];
            for (int mi = 0; mi < 4; mi++)
                a[mi] = *(const short8*)&As[(wm + mi * 16 + l16) * 64 + slot];
            for (int ni = 0; ni < 4; ni++)
                b[ni] = *(const short8*)&Bs[(wn + ni * 16 + l16) * 64 + slot];
            for (int mi = 0; mi < 4; mi++)
                for (int ni = 0; ni < 4; ni++)
                    acc[mi][ni] = __builtin_amdgcn_mfma_f32_16x16x32_bf16(
                        a[mi], b[ni], acc[mi][ni], 0, 0, 0);
        }
    }

    for (int mi = 0; mi < 4; mi++) {
        for (int ni = 0; ni < 4; ni++) {
            const int col = bn + wn + ni * 16 + l16;
            const float bv = bf2f(pb[PB_BPROJ + col]);
            for (int r = 0; r < 4; r++) {
                const int row = bm + wm + mi * 16 + quad * 4 + r;
                const float v = acc[mi][ni][r] + bv;
                if (isf) ((float*)out)[(size_t)row * C_SZ + col] = v;
                else     ((u16*)out)[(size_t)row * C_SZ + col] = f2bf(v);
            }
        }
    }
}

extern "C" void kernel_launch(void* const* d_in, const int* in_sizes, int n_in,
                              void* d_out, int out_size, void* d_ws, size_t ws_size,
                              hipStream_t stream) {
    const void* x     = d_in[0];
    const void* Wqkv  = d_in[1];
    const void* bqkv  = d_in[2];
    const void* Wproj = d_in[3];
    const void* bproj = d_in[4];
    const void* qsc   = d_in[5];
    const void* qbi   = d_in[6];
    const void* ksc   = d_in[7];
    const void* kbi   = d_in[8];

    u16* ws = (u16*)d_ws;
    int* flag    = (int*)d_ws;
    u16* xb      = ws + OFF_XB;
    u16* Wt_qkv  = ws + OFF_WQT;
    u16* Wt_proj = ws + OFF_WPT;
    u16* pb      = ws + OFF_PB;
    u16* Qb      = ws + OFF_Q;
    u16* Kb      = ws + OFF_K;
    u16* Vb      = ws + OFF_V;     // [B,NH,HD,T]
    u16* Yb      = ws + OFF_Y;

    prep_k<<<12296, 256, 0, stream>>>(x, Wqkv, Wproj, bqkv, bproj,
                                      qsc, qbi, ksc, kbi,
                                      xb, Wt_qkv, Wt_proj, pb, flag);
    qkv_gemm<<<dim3(24, 64), 256, 0, stream>>>(xb, Wt_qkv, pb, Qb, Kb, Vb);
    attn_k<<<dim3(512), 512, 0, stream>>>(Qb, Kb, Vb, Yb);
    proj_gemm<<<dim3(8, 64), 256, 0, stream>>>(Yb, Wt_proj, pb, d_out, flag);
}